// Round 1
// 422.333 us; speedup vs baseline: 1.0703x; 1.0703x over previous
//
#include <hip/hip_runtime.h>
#include <math.h>

#define LL 2048
#define BB 128
#define HH 300
#define HV4 75   // HH / 4

// Kernel 1: v_t[b][h] = sum_k W[k][h] * hidden[k][b]   (bias dropped: softmax-shift-invariant)
// K split 4-ways across the 4 waves of the block, LDS reduce.
// Grid = BB * 5 blocks (5 tiles of 64 h), 256 threads: >=2 blocks/CU vs the old 150-block launch.
__global__ void __launch_bounds__(256) compute_v(const float* __restrict__ W,
                                                 const float* __restrict__ hidden,
                                                 float* __restrict__ v_t) {
    int blk  = blockIdx.x;
    int b    = blk / 5;
    int h0   = (blk - b * 5) * 64;
    int wave = threadIdx.x >> 6;   // k-chunk index, 4 chunks of 75
    int lane = threadIdx.x & 63;
    int h    = h0 + lane;

    float s = 0.f;
    if (h < HH) {
        const float* Wp = W      + (size_t)wave * 75 * HH + h;   // coalesced over lane
        const float* hp = hidden + (size_t)wave * 75 * BB + b;   // wave-broadcast
#pragma unroll 5
        for (int k = 0; k < 75; ++k)
            s = fmaf(Wp[k * HH], hp[k * BB], s);
    }
    __shared__ float red[4][64];
    red[wave][lane] = s;
    __syncthreads();
    if (wave == 0 && h < HH)
        v_t[b * HH + h] = red[0][lane] + red[1][lane] + red[2][lane] + red[3][lane];
}

// Kernel 2 (the 315 MB stream): one wave per (l,b) row, 4 consecutive rows per block
// so the global read stream stays contiguous (4.8 KB per block).
// Stores go directly to the FINAL [B][L] layout in d_out (4B scattered stores, 1 MB
// total, absorbed by L2) so the softmax can read/write coalesced in place.
__global__ void __launch_bounds__(256) compute_energies(
        const float4* __restrict__ qv4,
        const float4* __restrict__ v4,
        float* __restrict__ out) {
    int wave = threadIdx.x >> 6;
    int lane = threadIdx.x & 63;
    int row  = blockIdx.x * 4 + wave;          // row = l*BB + b, contiguous stream
    int b    = row & (BB - 1);
    int l    = row >> 7;

    const float4* q = qv4 + (size_t)row * HV4;
    const float4* v = v4  + (size_t)b   * HV4;

    float4 a0 = q[lane];
    float4 b0 = v[lane];
    float s = a0.x * b0.x + a0.y * b0.y + a0.z * b0.z + a0.w * b0.w;
    if (lane < HV4 - 64) {                     // lanes 0..10 cover elements 64..74
        float4 a1 = q[64 + lane];
        float4 b1 = v[64 + lane];
        s += a1.x * b1.x + a1.y * b1.y + a1.z * b1.z + a1.w * b1.w;
    }
#pragma unroll
    for (int off = 32; off > 0; off >>= 1)
        s += __shfl_down(s, off, 64);
    if (lane == 0)
        out[(size_t)b * LL + l] = s;           // transposed store: final [B][L] layout
}

// Kernel 3: in-place softmax over out[b*LL .. b*LL+2047]. Fully coalesced float4
// reads/writes (each block owns exactly its own segment -> no cross-block hazard).
__global__ void __launch_bounds__(256) softmax_inplace(float* __restrict__ out) {
    int b    = blockIdx.x;
    int tid  = threadIdx.x;
    int lane = tid & 63;
    int wave = tid >> 6;

    float4* p = (float4*)(out + (size_t)b * LL);   // 512 float4 per row

    float4 x0 = p[tid];
    float4 x1 = p[tid + 256];

    float m = fmaxf(fmaxf(fmaxf(x0.x, x0.y), fmaxf(x0.z, x0.w)),
                    fmaxf(fmaxf(x1.x, x1.y), fmaxf(x1.z, x1.w)));
#pragma unroll
    for (int off = 32; off > 0; off >>= 1)
        m = fmaxf(m, __shfl_xor(m, off, 64));

    __shared__ float redm[4];
    __shared__ float reds[4];
    if (lane == 0) redm[wave] = m;
    __syncthreads();
    m = fmaxf(fmaxf(redm[0], redm[1]), fmaxf(redm[2], redm[3]));

    x0.x = __expf(x0.x - m); x0.y = __expf(x0.y - m);
    x0.z = __expf(x0.z - m); x0.w = __expf(x0.w - m);
    x1.x = __expf(x1.x - m); x1.y = __expf(x1.y - m);
    x1.z = __expf(x1.z - m); x1.w = __expf(x1.w - m);

    float s = (x0.x + x0.y + x0.z + x0.w) + (x1.x + x1.y + x1.z + x1.w);
#pragma unroll
    for (int off = 32; off > 0; off >>= 1)
        s += __shfl_xor(s, off, 64);
    if (lane == 0) reds[wave] = s;
    __syncthreads();
    s = reds[0] + reds[1] + reds[2] + reds[3];
    float inv = 1.f / s;

    x0.x *= inv; x0.y *= inv; x0.z *= inv; x0.w *= inv;
    x1.x *= inv; x1.y *= inv; x1.z *= inv; x1.w *= inv;
    p[tid]       = x0;
    p[tid + 256] = x1;
}

extern "C" void kernel_launch(void* const* d_in, const int* in_sizes, int n_in,
                              void* d_out, int out_size, void* d_ws, size_t ws_size,
                              hipStream_t stream) {
    const float* hidden = (const float*)d_in[0];   // [H, B]
    const float* qv     = (const float*)d_in[1];   // [L, B, H]
    const float* W      = (const float*)d_in[2];   // [H, H]
    // d_in[3] = bias[H]: adds a per-b constant along the softmax axis -> no-op. Unused.
    float* out = (float*)d_out;                    // [B, L] (leading 1 squeezed)

    float* v_t = (float*)d_ws;                     // BB*HH floats = 153.6 KB (only ws use)

    compute_v<<<BB * 5, 256, 0, stream>>>(W, hidden, v_t);
    compute_energies<<<(LL * BB) / 4, 256, 0, stream>>>(
        (const float4*)qv, (const float4*)v_t, out);
    softmax_inplace<<<BB, 256, 0, stream>>>(out);
}